// Round 1
// baseline (403.503 us; speedup 1.0000x reference)
//
#include <hip/hip_runtime.h>
#include <hip/hip_bf16.h>
#include <math.h>

// DCNv2 forward: offset/mod conv -> bilinear deform sample -> main conv -> bias+relu
// Shapes: x [4,64,192,192] f32; w_off [18,64,3,3]; b_off[18]; w_mod [9,64,3,3]; b_mod[9];
//         w [64,64,3,3]; b[64]; out [4,64,192,192] f32.

#define NB   4
#define CIN  64
#define COUT 64
#define HH   192
#define WW   192
#define HW   (HH*WW)
#define K2   9

__device__ __forceinline__ int iclamp(int v, int lo, int hi) {
    return v < lo ? lo : (v > hi ? hi : v);
}

// ---------------------------------------------------------------------------
// Kernel 0: weight repack.
//  wt[k][c][o]   (9*64*64)        : main conv weights, o contiguous per (k,c)
//  waux[r=c*9+kk][j(pad 28)]      : 27 aux output channels contiguous (j<18 off, j>=18 mod)
// ---------------------------------------------------------------------------
__global__ __launch_bounds__(256) void prep_weights(
        const float* __restrict__ w, const float* __restrict__ w_off,
        const float* __restrict__ w_mod, float* __restrict__ wt,
        float* __restrict__ waux) {
    int idx = blockIdx.x * 256 + threadIdx.x;
    if (idx < 9 * 64 * 64) {
        int k = idx / 4096;
        int r = idx % 4096;
        int c = r >> 6, o = r & 63;
        wt[idx] = w[(o * 64 + c) * 9 + k];      // w[o][c][k]
    }
    int i2 = idx - 9 * 64 * 64;
    if (i2 >= 0 && i2 < 576 * 28) {
        int r = i2 / 28, j = i2 % 28;           // r = c*9+kk
        float v = 0.f;
        if (j < 18)      v = w_off[j * 576 + r];
        else if (j < 27) v = w_mod[(j - 18) * 576 + r];
        waux[i2] = v;
    }
}

// ---------------------------------------------------------------------------
// Kernel 1: offset + modulation 3x3 conv (Cin=64 -> 27 channels).
// One thread per output pixel; 27 f32 accumulators; weights read with
// block-uniform addresses (compiler -> s_load broadcast).
// Output layout offmod[n][ch][h][w], ch: 0..17 raw offsets (y,x interleaved
// per tap), 18..26 modulation = 2*sigmoid(conv).
// ---------------------------------------------------------------------------
__global__ __launch_bounds__(192) void aux_conv(
        const float* __restrict__ x, const float* __restrict__ waux,
        const float* __restrict__ b_off, const float* __restrict__ b_mod,
        float* __restrict__ offmod) {
    int wo = threadIdx.x;       // 0..191
    int ho = blockIdx.x;        // 0..191
    int n  = blockIdx.y;        // 0..3

    float acc[27];
#pragma unroll
    for (int j = 0; j < 18; j++) acc[j] = b_off[j];
#pragma unroll
    for (int j = 0; j < 9; j++)  acc[18 + j] = b_mod[j];

    const float* xn = x + n * CIN * HW;
    for (int c = 0; c < CIN; c++) {
        const float* xc = xn + c * HW;
#pragma unroll
        for (int ky = 0; ky < 3; ky++) {
            int ys = ho + ky - 1;
            if ((unsigned)ys >= (unsigned)HH) continue;   // zero pad row (uniform branch)
#pragma unroll
            for (int kx = 0; kx < 3; kx++) {
                int xs = wo + kx - 1;
                float xv = ((unsigned)xs < (unsigned)WW) ? xc[ys * WW + xs] : 0.f;
                const float* wp = waux + (c * 9 + ky * 3 + kx) * 28;  // uniform address
#pragma unroll
                for (int j = 0; j < 27; j++)
                    acc[j] = fmaf(wp[j], xv, acc[j]);
            }
        }
    }

    float* om = offmod + (n * 27 * HH + ho) * WW + wo;
#pragma unroll
    for (int j = 0; j < 18; j++) om[j * HW] = acc[j];
#pragma unroll
    for (int j = 18; j < 27; j++) om[j * HW] = 2.f / (1.f + expf(-acc[j]));
}

// ---------------------------------------------------------------------------
// Kernel 2: deformable sampling + main conv + bias + relu.
// Block = 256 threads = 4 waves; tile = 64 consecutive wo at fixed (n, ho).
// Per tap k: wave g samples channels [16g,16g+16) into LDS val[c][l],
// then accumulates its 16 output channels: acc[j] += w[k][c][16g+j]*val[c][l].
// Weight reads are wave-uniform (readfirstlane) -> scalar loads.
// ---------------------------------------------------------------------------
__global__ __launch_bounds__(256) void dcn_main(
        const float* __restrict__ x, const float* __restrict__ wt,
        const float* __restrict__ bias, const float* __restrict__ offmod,
        float* __restrict__ out) {
    __shared__ float lds_val[64 * 64];   // val[c][l], 16 KB

    int tid = threadIdx.x;
    int l   = tid & 63;
    int grp = __builtin_amdgcn_readfirstlane(tid >> 6);  // wave-uniform 0..3
    int wo  = blockIdx.x * 64 + l;
    int ho  = blockIdx.y;
    int n   = blockIdx.z;

    const float* om = offmod + (n * 27 * HH + ho) * WW + wo;
    const float* xb = x + (n * CIN + grp * 16) * HW;

    float acc[16];
#pragma unroll
    for (int j = 0; j < 16; j++) acc[j] = 0.f;

    for (int k = 0; k < 9; k++) {
        // --- sampling parameters for this pixel & tap ---
        float offy = om[(2 * k) * HW];
        float offx = om[(2 * k + 1) * HW];
        float mm   = om[(18 + k) * HW];
        float py = offy + (float)(ho - 1 + k / 3);
        float px = offx + (float)(wo - 1 + k % 3);
        float y0f = floorf(py), x0f = floorf(px);
        float ly = py - y0f, lx = px - x0f;
        int y0 = (int)y0f, x0 = (int)x0f;
        int y1 = y0 + 1, x1 = x0 + 1;
        bool y0ok = (unsigned)y0 < (unsigned)HH, y1ok = (unsigned)y1 < (unsigned)HH;
        bool x0ok = (unsigned)x0 < (unsigned)WW, x1ok = (unsigned)x1 < (unsigned)WW;
        float w00 = (y0ok && x0ok) ? (1.f - ly) * (1.f - lx) : 0.f;
        float w01 = (y0ok && x1ok) ? (1.f - ly) * lx         : 0.f;
        float w10 = (y1ok && x0ok) ? ly * (1.f - lx)         : 0.f;
        float w11 = (y1ok && x1ok) ? ly * lx                 : 0.f;
        int y0c = iclamp(y0, 0, HH - 1), y1c = iclamp(y1, 0, HH - 1);
        int x0c = iclamp(x0, 0, WW - 1), x1c = iclamp(x1, 0, WW - 1);
        int o00 = y0c * WW + x0c, o01 = y0c * WW + x1c;
        int o10 = y1c * WW + x0c, o11 = y1c * WW + x1c;

        // --- bilinear sample 16 channels into LDS ---
#pragma unroll
        for (int i = 0; i < 16; i++) {
            const float* xc = xb + i * HW;
            float v = w00 * xc[o00] + w01 * xc[o01] + w10 * xc[o10] + w11 * xc[o11];
            lds_val[(grp * 16 + i) * 64 + l] = v * mm;
        }
        __syncthreads();

        // --- accumulate 16 output channels over all 64 input channels ---
        const float* wk = wt + k * 4096 + grp * 16;   // wave-uniform base
#pragma unroll 8
        for (int c = 0; c < 64; c++) {
            float v = lds_val[c * 64 + l];
            const float* wr = wk + c * 64;            // uniform -> s_load
#pragma unroll
            for (int j = 0; j < 16; j++)
                acc[j] = fmaf(wr[j], v, acc[j]);
        }
        __syncthreads();
    }

#pragma unroll
    for (int j = 0; j < 16; j++) {
        int o = grp * 16 + j;
        float r = acc[j] + bias[o];
        out[((n * COUT + o) * HH + ho) * WW + wo] = fmaxf(r, 0.f);
    }
}

// ---------------------------------------------------------------------------
extern "C" void kernel_launch(void* const* d_in, const int* in_sizes, int n_in,
                              void* d_out, int out_size, void* d_ws, size_t ws_size,
                              hipStream_t stream) {
    const float* x     = (const float*)d_in[0];
    const float* w_off = (const float*)d_in[1];
    const float* b_off = (const float*)d_in[2];
    const float* w_mod = (const float*)d_in[3];
    const float* b_mod = (const float*)d_in[4];
    const float* w     = (const float*)d_in[5];
    const float* b     = (const float*)d_in[6];
    float* out = (float*)d_out;

    // workspace layout (floats): wt[9*64*64] | waux[576*28] | offmod[4*27*192*192]
    float* wt     = (float*)d_ws;
    float* waux   = wt + 9 * 64 * 64;
    float* offmod = waux + 576 * 28;

    prep_weights<<<dim3(207), dim3(256), 0, stream>>>(w, w_off, w_mod, wt, waux);
    aux_conv<<<dim3(HH, NB), dim3(192), 0, stream>>>(x, waux, b_off, b_mod, offmod);
    dcn_main<<<dim3(WW / 64, HH, NB), dim3(256), 0, stream>>>(x, wt, b, offmod, out);
}

// Round 2
// 325.457 us; speedup vs baseline: 1.2398x; 1.2398x over previous
//
#include <hip/hip_runtime.h>
#include <hip/hip_bf16.h>
#include <math.h>

// DCNv2 forward: offset/mod conv -> bilinear deform sample -> main conv (bf16 MFMA)
// Shapes: x [4,64,192,192] f32; w_off [18,64,3,3]; b_off[18]; w_mod [9,64,3,3]; b_mod[9];
//         w [64,64,3,3]; b[64]; out [4,64,192,192] f32.

#define NB   4
#define CIN  64
#define COUT 64
#define HH   192
#define WW   192
#define HW   (HH*WW)

typedef __attribute__((ext_vector_type(4))) float f32x4;
typedef __attribute__((ext_vector_type(8))) short bf16x8;
typedef __attribute__((ext_vector_type(4))) unsigned int u32x4;

__device__ __forceinline__ int iclamp(int v, int lo, int hi) {
    return v < lo ? lo : (v > hi ? hi : v);
}
__device__ __forceinline__ unsigned short bf16bits(float f) {
    __hip_bfloat16 h = __float2bfloat16(f);
    return *reinterpret_cast<unsigned short*>(&h);
}

// ---------------------------------------------------------------------------
// Kernel 0: weight repack.
//  wfrag: main weights in MFMA A-fragment order, bf16.
//    A tile for (tap k, wave g, K-chunk kc) is 16(o) x 32(c):
//    lane l holds A[o=l&15][c = kc*32 + (l>>4)*8 + j], j=0..7  (bf16x8, 16B/lane)
//    flat bf16 index = (((k*4+g)*2+kc)*64 + l)*8 + j            (36864 total)
//  waux[r=c*9+kk][j(pad 28)]: 27 aux output channels contiguous (j<18 off, j>=18 mod)
// ---------------------------------------------------------------------------
__global__ __launch_bounds__(256) void prep_weights(
        const float* __restrict__ w, const float* __restrict__ w_off,
        const float* __restrict__ w_mod, __hip_bfloat16* __restrict__ wfrag,
        float* __restrict__ waux) {
    int idx = blockIdx.x * 256 + threadIdx.x;
    if (idx < 36864) {
        int j    = idx & 7;
        int lane = (idx >> 3) & 63;
        int kc   = (idx >> 9) & 1;
        int g    = (idx >> 10) & 3;
        int k    = idx >> 12;
        int o = g * 16 + (lane & 15);
        int c = kc * 32 + (lane >> 4) * 8 + j;
        wfrag[idx] = __float2bfloat16(w[(o * 64 + c) * 9 + k]);
    }
    if (idx < 576 * 28) {
        int r = idx / 28, j = idx % 28;           // r = c*9+kk
        float v = 0.f;
        if (j < 18)      v = w_off[j * 576 + r];
        else if (j < 27) v = w_mod[(j - 18) * 576 + r];
        waux[idx] = v;
    }
}

// ---------------------------------------------------------------------------
// Kernel 1: offset + modulation 3x3 conv (Cin=64 -> 27 channels).
// One thread per output pixel; weights block-uniform -> s_load broadcast.
// XCD-swizzled 1D grid (768 blocks, 768%8==0): each XCD owns 96 contiguous rows.
// ---------------------------------------------------------------------------
__global__ __launch_bounds__(192) void aux_conv(
        const float* __restrict__ x, const float* __restrict__ waux,
        const float* __restrict__ b_off, const float* __restrict__ b_mod,
        float* __restrict__ offmod) {
    int id = blockIdx.x;                       // 0..767
    int sw = (id & 7) * 96 + (id >> 3);        // bijective XCD swizzle
    int n  = sw / HH;
    int ho = sw % HH;
    int wo = threadIdx.x;                      // 0..191

    float acc[27];
#pragma unroll
    for (int j = 0; j < 18; j++) acc[j] = b_off[j];
#pragma unroll
    for (int j = 0; j < 9; j++)  acc[18 + j] = b_mod[j];

    const float* xn = x + n * CIN * HW;
    for (int c = 0; c < CIN; c++) {
        const float* xc = xn + c * HW;
#pragma unroll
        for (int ky = 0; ky < 3; ky++) {
            int ys = ho + ky - 1;
            if ((unsigned)ys >= (unsigned)HH) continue;
#pragma unroll
            for (int kx = 0; kx < 3; kx++) {
                int xs = wo + kx - 1;
                float xv = ((unsigned)xs < (unsigned)WW) ? xc[ys * WW + xs] : 0.f;
                const float* wp = waux + (c * 9 + ky * 3 + kx) * 28;  // uniform address
#pragma unroll
                for (int j = 0; j < 27; j++)
                    acc[j] = fmaf(wp[j], xv, acc[j]);
            }
        }
    }

    float* om = offmod + (n * 27 * HH + ho) * WW + wo;
#pragma unroll
    for (int j = 0; j < 18; j++) om[j * HW] = acc[j];
#pragma unroll
    for (int j = 18; j < 27; j++) om[j * HW] = 2.f / (1.f + expf(-acc[j]));
}

// ---------------------------------------------------------------------------
// Kernel 2: deformable sampling + bf16-MFMA main conv + bias + relu.
// Block = 256 thr = 4 waves; tile = 64 px (one ho, 64 consecutive wo).
// Per tap k: wave g bilinearly samples channels [16g,16g+16) for its lane's
// pixel, packs bf16, writes LDS val[p][c] (XOR-swizzled, double-buffered);
// then each wave computes its 16 out-channels x 64 px with 8 MFMA.
// XCD-swizzled 1D grid (2304 blocks): each XCD owns 96 contiguous ho rows
// of one image -> x streams through its private L2.
// ---------------------------------------------------------------------------
__global__ __launch_bounds__(256) void dcn_main(
        const float* __restrict__ x, const __hip_bfloat16* __restrict__ wfrag,
        const float* __restrict__ bias, const float* __restrict__ offmod,
        float* __restrict__ out) {
    // val[p=0..63][c=0..63] bf16, row = 128 B, XOR-swizzled, double buffered
    __shared__ __align__(16) char lds[2][64 * 128];

    int tid = threadIdx.x;
    int l   = tid & 63;
    int g   = __builtin_amdgcn_readfirstlane(tid >> 6);  // wave 0..3

    int id = blockIdx.x;                        // 0..2303
    int sw = (id & 7) * 288 + (id >> 3);        // bijective XCD swizzle
    int n  = sw / 576;
    int r  = sw % 576;
    int ho = r / 3;
    int wx = r % 3;
    int wo = wx * 64 + l;

    const float* om = offmod + (n * 27 * HH + ho) * WW + wo;
    const float* xb = x + (n * CIN + g * 16) * HW;

    f32x4 acc[4];
#pragma unroll
    for (int nf = 0; nf < 4; nf++) acc[nf] = (f32x4){0.f, 0.f, 0.f, 0.f};

    int xorw = (l & 7) << 4;                    // write-side swizzle (row = l)

#pragma unroll
    for (int k = 0; k < 9; k++) {
        // --- sampling parameters for this pixel & tap ---
        float offy = om[(2 * k) * HW];
        float offx = om[(2 * k + 1) * HW];
        float mm   = om[(18 + k) * HW];
        float py = offy + (float)(ho - 1 + k / 3);
        float px = offx + (float)(wo - 1 + k % 3);
        float y0f = floorf(py), x0f = floorf(px);
        float ly = py - y0f, lx = px - x0f;
        int y0 = (int)y0f, x0 = (int)x0f;
        int y1 = y0 + 1, x1 = x0 + 1;
        bool y0ok = (unsigned)y0 < (unsigned)HH, y1ok = (unsigned)y1 < (unsigned)HH;
        bool x0ok = (unsigned)x0 < (unsigned)WW, x1ok = (unsigned)x1 < (unsigned)WW;
        float w00 = (y0ok && x0ok) ? (1.f - ly) * (1.f - lx) : 0.f;
        float w01 = (y0ok && x1ok) ? (1.f - ly) * lx         : 0.f;
        float w10 = (y1ok && x0ok) ? ly * (1.f - lx)         : 0.f;
        float w11 = (y1ok && x1ok) ? ly * lx                 : 0.f;
        int y0c = iclamp(y0, 0, HH - 1), y1c = iclamp(y1, 0, HH - 1);
        int x0c = iclamp(x0, 0, WW - 1), x1c = iclamp(x1, 0, WW - 1);
        int o00 = y0c * WW + x0c, o01 = y0c * WW + x1c;
        int o10 = y1c * WW + x0c, o11 = y1c * WW + x1c;

        // --- bilinear sample 16 channels, pack bf16, write LDS row l ---
        union { unsigned short us[16]; u32x4 q[2]; } pk;
#pragma unroll
        for (int i = 0; i < 16; i++) {
            const float* xc = xb + i * HW;
            float v = xc[o00] * w00;
            v = fmaf(xc[o01], w01, v);
            v = fmaf(xc[o10], w10, v);
            v = fmaf(xc[o11], w11, v);
            pk.us[i] = bf16bits(v * mm);
        }
        char* buf = lds[k & 1];
        int b0 = l * 128 + g * 32;
        *(u32x4*)(buf + ((b0)      ^ xorw)) = pk.q[0];
        *(u32x4*)(buf + ((b0 + 16) ^ xorw)) = pk.q[1];

        // --- A fragments (L2-resident, perfectly coalesced 16B/lane) ---
        const bf16x8* wf = ((const bf16x8*)wfrag) + ((k * 4 + g) * 2) * 64 + l;
        bf16x8 a0 = wf[0];
        bf16x8 a1 = wf[64];

        __syncthreads();

        // --- 8 MFMA: D[o=16g..][p] += A(16x32) * V(32x64) over kc ---
#pragma unroll
        for (int nf = 0; nf < 4; nf++) {
            int p = nf * 16 + (l & 15);
            int base = p * 128 + ((l >> 4) * 16);
            int xorr = (p & 7) << 4;
            bf16x8 bv0 = *(const bf16x8*)(buf + ((base)      ^ xorr));
            bf16x8 bv1 = *(const bf16x8*)(buf + ((base + 64) ^ xorr));
            acc[nf] = __builtin_amdgcn_mfma_f32_16x16x32_bf16(a0, bv0, acc[nf], 0, 0, 0);
            acc[nf] = __builtin_amdgcn_mfma_f32_16x16x32_bf16(a1, bv1, acc[nf], 0, 0, 0);
        }
        // no second barrier: next tap writes the other LDS buffer; the
        // following tap's barrier orders reuse (double-buffer discipline)
    }

    // --- epilogue: bias + relu, D mapping col=lane&15, row=(lane>>4)*4+reg ---
#pragma unroll
    for (int nf = 0; nf < 4; nf++) {
#pragma unroll
        for (int rr = 0; rr < 4; rr++) {
            int o = g * 16 + (l >> 4) * 4 + rr;
            int p = nf * 16 + (l & 15);
            float v = acc[nf][rr] + bias[o];
            out[((n * COUT + o) * HH + ho) * WW + wx * 64 + p] = fmaxf(v, 0.f);
        }
    }
}

// ---------------------------------------------------------------------------
extern "C" void kernel_launch(void* const* d_in, const int* in_sizes, int n_in,
                              void* d_out, int out_size, void* d_ws, size_t ws_size,
                              hipStream_t stream) {
    const float* x     = (const float*)d_in[0];
    const float* w_off = (const float*)d_in[1];
    const float* b_off = (const float*)d_in[2];
    const float* w_mod = (const float*)d_in[3];
    const float* b_mod = (const float*)d_in[4];
    const float* w     = (const float*)d_in[5];
    const float* b     = (const float*)d_in[6];
    float* out = (float*)d_out;

    // ws layout: offmod f32[4*27*HW] | waux f32[576*28] | wfrag bf16[36864]
    float* offmod = (float*)d_ws;
    float* waux   = offmod + NB * 27 * HW;
    __hip_bfloat16* wfrag = (__hip_bfloat16*)(waux + 576 * 28);

    prep_weights<<<dim3(144), dim3(256), 0, stream>>>(w, w_off, w_mod, wfrag, waux);
    aux_conv<<<dim3(768), dim3(192), 0, stream>>>(x, waux, b_off, b_mod, offmod);
    dcn_main<<<dim3(2304), dim3(256), 0, stream>>>(x, wfrag, b, offmod, out);
}